// Round 1
// baseline (296304.834 us; speedup 1.0000x reference)
//
#include <hip/hip_runtime.h>
#include <hip/hip_bf16.h>
#include <stdint.h>

typedef __attribute__((ext_vector_type(8))) short short8;
typedef __attribute__((ext_vector_type(4))) float f32x4;

__device__ __forceinline__ unsigned short f2bf(float f) {
  union { float f; unsigned u; } v; v.f = f;
  unsigned r = v.u + 0x7FFFu + ((v.u >> 16) & 1u);
  return (unsigned short)(r >> 16);
}
__device__ __forceinline__ float bf2f(unsigned short h) {
  union { unsigned u; float f; } v; v.u = ((unsigned)h) << 16;
  return v.f;
}
__device__ __forceinline__ float sigm(float x) {
  x = fminf(fmaxf(x, -30.f), 30.f);
  return 1.f / (1.f + __expf(-x));
}
__device__ __forceinline__ float tanh_(float x) {
  x = fminf(fmaxf(x, -15.f), 15.f);
  float t = __expf(2.f * x);
  return (t - 1.f) / (t + 1.f);
}
__device__ __forceinline__ short8 pack8(float4 u, float4 v) {
  short8 r;
  r[0] = (short)f2bf(u.x); r[1] = (short)f2bf(u.y); r[2] = (short)f2bf(u.z); r[3] = (short)f2bf(u.w);
  r[4] = (short)f2bf(v.x); r[5] = (short)f2bf(v.y); r[6] = (short)f2bf(v.z); r[7] = (short)f2bf(v.w);
  return r;
}

// C[M,N] bf16 = A[M,K] f32 * B[N,K]^T f32 + bias[N].  M,N mult of 128, K mult of 32.
__global__ __launch_bounds__(256) void gemm_nt_bias(
    const float* __restrict__ A, const float* __restrict__ B,
    const float* __restrict__ bias, unsigned short* __restrict__ C,
    int M, int N, int K)
{
  __shared__ __align__(16) short As[128 * 32];
  __shared__ __align__(16) short Bs[128 * 32];
  const int tid = threadIdx.x;
  const int lane = tid & 63, w = tid >> 6;
  const int brow = blockIdx.x * 128, bcol = blockIdx.y * 128;
  const int wrow = (w & 1) * 64, wcol = (w >> 1) * 64;
  const int c16 = lane & 15, kg = lane >> 4;
  f32x4 acc[4][4];
#pragma unroll
  for (int m = 0; m < 4; m++)
#pragma unroll
    for (int n = 0; n < 4; n++) { f32x4 z = {0.f, 0.f, 0.f, 0.f}; acc[m][n] = z; }

  const int lrow = tid >> 1, lk = (tid & 1) * 16;
  const float* ap = A + (size_t)(brow + lrow) * K + lk;
  const float* bp = B + (size_t)(bcol + lrow) * K + lk;
  short* asw = &As[lrow * 32 + lk];
  short* bsw = &Bs[lrow * 32 + lk];

  for (int kb = 0; kb < K; kb += 32) {
    float4 a0 = *(const float4*)(ap + kb);
    float4 a1 = *(const float4*)(ap + kb + 4);
    float4 a2 = *(const float4*)(ap + kb + 8);
    float4 a3 = *(const float4*)(ap + kb + 12);
    float4 b0 = *(const float4*)(bp + kb);
    float4 b1 = *(const float4*)(bp + kb + 4);
    float4 b2 = *(const float4*)(bp + kb + 8);
    float4 b3 = *(const float4*)(bp + kb + 12);
    __syncthreads();  // prior iteration's LDS reads done
    *(short8*)asw = pack8(a0, a1);
    *(short8*)(asw + 8) = pack8(a2, a3);
    *(short8*)bsw = pack8(b0, b1);
    *(short8*)(bsw + 8) = pack8(b2, b3);
    __syncthreads();
    short8 af[4], bf[4];
#pragma unroll
    for (int m = 0; m < 4; m++) af[m] = *(const short8*)&As[(wrow + m * 16 + c16) * 32 + kg * 8];
#pragma unroll
    for (int n = 0; n < 4; n++) bf[n] = *(const short8*)&Bs[(wcol + n * 16 + c16) * 32 + kg * 8];
#pragma unroll
    for (int m = 0; m < 4; m++)
#pragma unroll
      for (int n = 0; n < 4; n++)
        acc[m][n] = __builtin_amdgcn_mfma_f32_16x16x32_bf16(af[m], bf[n], acc[m][n], 0, 0, 0);
  }
#pragma unroll
  for (int n = 0; n < 4; n++) {
    const int col = bcol + wcol + n * 16 + c16;
    const float bv = bias[col];
#pragma unroll
    for (int m = 0; m < 4; m++) {
#pragma unroll
      for (int i = 0; i < 4; i++) {
        const int row = brow + wrow + m * 16 + kg * 4 + i;
        C[(size_t)row * N + col] = f2bf(acc[m][n][i] + bv);
      }
    }
  }
}

// Bidirectional GRU encoder scan. One 12-wave workgroup per direction.
// Whh (1152x384) lives in VGPRs as bf16 MFMA B-fragments (288 VGPR/lane).
// Gate-matched tiles: wave w owns i-tiles {2w,2w+1} for all 3 gates.
__global__ __launch_bounds__(768, 3) void enc_scan(
    const float* __restrict__ WhhF, const float* __restrict__ bhhF,
    const float* __restrict__ WhhB, const float* __restrict__ bhhB,
    const unsigned short* __restrict__ Gf, const unsigned short* __restrict__ Gb,
    unsigned short* __restrict__ outputs, int L, int dir0)
{
  const int dir = blockIdx.x + dir0;
  const float* Whh = dir ? WhhB : WhhF;
  const float* bhh = dir ? bhhB : bhhF;
  const unsigned short* G = dir ? Gb : Gf;
  const int tid = threadIdx.x, lane = tid & 63, w = tid >> 6;
  const int c16 = lane & 15, kg = lane >> 4;
  __shared__ __align__(16) unsigned short h_lds[384];

  short8 wf[3][2][12];
  float bb[3][2];
#pragma unroll
  for (int g = 0; g < 3; g++)
#pragma unroll
    for (int d = 0; d < 2; d++) {
      const int j = g * 384 + (2 * w + d) * 16 + c16;
      bb[g][d] = bhh[j];
      const float* rowp = Whh + (size_t)j * 384 + kg * 8;
#pragma unroll
      for (int t = 0; t < 12; t++) {
        float4 x0 = *(const float4*)(rowp + t * 32);
        float4 x1 = *(const float4*)(rowp + t * 32 + 4);
        wf[g][d][t] = pack8(x0, x1);
      }
    }
  float h_own[2] = {0.f, 0.f};
  if (tid < 384) h_lds[tid] = 0;
  __syncthreads();

  for (int si = 0; si < L; ++si) {
    const int s = dir ? (L - 1 - si) : si;
    const unsigned short* gp = G + (size_t)s * 1152;
    float gi[3][2];
#pragma unroll
    for (int g = 0; g < 3; g++)
#pragma unroll
      for (int d = 0; d < 2; d++)
        gi[g][d] = bf2f(gp[g * 384 + (2 * w + d) * 16 + c16]);

    f32x4 acc[3][2];
#pragma unroll
    for (int g = 0; g < 3; g++)
#pragma unroll
      for (int d = 0; d < 2; d++) { f32x4 t = {bb[g][d], bb[g][d], bb[g][d], bb[g][d]}; acc[g][d] = t; }
#pragma unroll
    for (int t = 0; t < 12; t++) {
      short8 a = *(const short8*)&h_lds[t * 32 + kg * 8];  // broadcast A-frag (rows replicated)
#pragma unroll
      for (int g = 0; g < 3; g++)
#pragma unroll
        for (int d = 0; d < 2; d++)
          acc[g][d] = __builtin_amdgcn_mfma_f32_16x16x32_bf16(a, wf[g][d][t], acc[g][d], 0, 0, 0);
    }
    __syncthreads();  // all h_lds reads done
#pragma unroll
    for (int d = 0; d < 2; d++) {
      const float r = sigm(gi[0][d] + acc[0][d][0]);
      const float z = sigm(gi[1][d] + acc[1][d][0]);
      const float n = tanh_(gi[2][d] + r * acc[2][d][0]);
      h_own[d] = (1.f - z) * n + z * h_own[d];
    }
    if (lane < 16) {
#pragma unroll
      for (int d = 0; d < 2; d++) {
        const int i = (2 * w + d) * 16 + c16;
        const unsigned short hb = f2bf(h_own[d]);
        h_lds[i] = hb;
        outputs[(size_t)s * 768 + dir * 384 + i] = hb;
      }
    }
    __syncthreads();  // h_new visible
  }
}

// Decoder GRU scan: 4 cooperating WGs (12 waves each), dec_whh split by output slice,
// per-step handshake through device-scope atomics in d_ws.
__global__ __launch_bounds__(768, 3) void dec_scan(
    const float* __restrict__ Whh, const float* __restrict__ bhh,
    const unsigned short* __restrict__ Gd, const float* __restrict__ hinit,
    unsigned int* __restrict__ hbuf32, int* __restrict__ ctr,
    float* __restrict__ dechs, int Ksteps)
{
  const int wg = blockIdx.x;
  const int tid = threadIdx.x, lane = tid & 63, w = tid >> 6;
  const int c16 = lane & 15, kg = lane >> 4;
  const int itile = wg * 12 + w;
  const int i = itile * 16 + c16;
  __shared__ __align__(16) unsigned short h_lds[768];

  short8 wf[3][24];
  float bb[3];
#pragma unroll
  for (int g = 0; g < 3; g++) {
    const int j = g * 768 + i;
    bb[g] = bhh[j];
    const float* rowp = Whh + (size_t)j * 768 + kg * 8;
#pragma unroll
    for (int t = 0; t < 24; t++) {
      float4 x0 = *(const float4*)(rowp + t * 32);
      float4 x1 = *(const float4*)(rowp + t * 32 + 4);
      wf[g][t] = pack8(x0, x1);
    }
  }
  float h_own = hinit[i];
  h_lds[tid] = f2bf(hinit[tid]);
  __syncthreads();

  for (int s = 0; s < Ksteps; ++s) {
    float gi[3];
#pragma unroll
    for (int g = 0; g < 3; g++) gi[g] = bf2f(Gd[(size_t)s * 2304 + g * 768 + i]);
    f32x4 acc[3];
#pragma unroll
    for (int g = 0; g < 3; g++) { f32x4 t = {bb[g], bb[g], bb[g], bb[g]}; acc[g] = t; }
#pragma unroll
    for (int t = 0; t < 24; t++) {
      short8 a = *(const short8*)&h_lds[t * 32 + kg * 8];
#pragma unroll
      for (int g = 0; g < 3; g++)
        acc[g] = __builtin_amdgcn_mfma_f32_16x16x32_bf16(a, wf[g][t], acc[g], 0, 0, 0);
    }
    __syncthreads();
    {
      const float r = sigm(gi[0] + acc[0][0]);
      const float z = sigm(gi[1] + acc[1][0]);
      const float n = tanh_(gi[2] + r * acc[2][0]);
      h_own = (1.f - z) * n + z * h_own;
    }
    const unsigned short hb = f2bf(h_own);
    const int partner = __shfl_down((int)hb, 1);
    unsigned int* outb = hbuf32 + (s & 1) * 384;
    if (lane < 16) {
      dechs[(size_t)s * 768 + i] = h_own;
      if ((c16 & 1) == 0)
        __hip_atomic_store(&outb[i >> 1],
                           ((unsigned)hb & 0xFFFFu) | (((unsigned)partner & 0xFFFFu) << 16),
                           __ATOMIC_RELAXED, __HIP_MEMORY_SCOPE_AGENT);
    }
    __threadfence();
    __syncthreads();
    if (tid == 0) {
      __hip_atomic_fetch_add(&ctr[s], 1, __ATOMIC_RELEASE, __HIP_MEMORY_SCOPE_AGENT);
      while (__hip_atomic_load(&ctr[s], __ATOMIC_ACQUIRE, __HIP_MEMORY_SCOPE_AGENT) < 4)
        __builtin_amdgcn_s_sleep(8);
    }
    __syncthreads();
    if (tid < 384) {
      unsigned v = __hip_atomic_load(&outb[tid], __ATOMIC_RELAXED, __HIP_MEMORY_SCOPE_AGENT);
      ((unsigned*)h_lds)[tid] = v;
    }
    __syncthreads();
  }
}

__global__ void gather_dec(const unsigned short* __restrict__ outputs,
                           const int* __restrict__ breaks,
                           float* __restrict__ dec_in, float* __restrict__ hinit,
                           int L, int K)
{
  const int b = blockIdx.x;
  if (b < K) {
    const int start = (b == 0) ? 0 : breaks[b - 1];
    const unsigned short* src = outputs + (size_t)start * 768;
    for (int d = threadIdx.x; d < 768; d += blockDim.x)
      dec_in[(size_t)b * 768 + d] = bf2f(src[d]);
  } else {
    const unsigned short* src = outputs + (size_t)(L - 1) * 768;
    for (int d = threadIdx.x; d < 768; d += blockDim.x)
      hinit[d] = bf2f(src[d]);
  }
}

// Per-break masked log-softmax over outputs[start:] + NLL at target.
__global__ __launch_bounds__(256) void loss_kernel(
    const unsigned short* __restrict__ outputs, const float* __restrict__ dechs,
    const int* __restrict__ breaks, float* __restrict__ lossk, int L)
{
  const int k = blockIdx.x;
  const int start = (k == 0) ? 0 : breaks[k - 1];
  const int target = breaks[k];
  __shared__ float dh[768];
  __shared__ float tgt_sh;
  __shared__ float wm[4], wss[4];
  for (int d = threadIdx.x; d < 768; d += 256) dh[d] = dechs[(size_t)k * 768 + d];
  if (threadIdx.x == 0) tgt_sh = 0.f;
  __syncthreads();

  float m = -3.4e38f, ss = 0.f;
  for (int p = start + threadIdx.x; p < L; p += 256) {
    const uint4* r4 = (const uint4*)(outputs + (size_t)p * 768);
    float dot = 0.f;
#pragma unroll 4
    for (int q = 0; q < 96; ++q) {
      const uint4 u = r4[q];
      const int d = q * 8;
      dot += bf2f((unsigned short)(u.x & 0xFFFF)) * dh[d + 0];
      dot += bf2f((unsigned short)(u.x >> 16)) * dh[d + 1];
      dot += bf2f((unsigned short)(u.y & 0xFFFF)) * dh[d + 2];
      dot += bf2f((unsigned short)(u.y >> 16)) * dh[d + 3];
      dot += bf2f((unsigned short)(u.z & 0xFFFF)) * dh[d + 4];
      dot += bf2f((unsigned short)(u.z >> 16)) * dh[d + 5];
      dot += bf2f((unsigned short)(u.w & 0xFFFF)) * dh[d + 6];
      dot += bf2f((unsigned short)(u.w >> 16)) * dh[d + 7];
    }
    if (p == target) tgt_sh = dot;
    if (dot > m) { ss = ss * __expf(m - dot) + 1.f; m = dot; }
    else ss += __expf(dot - m);
  }
#pragma unroll
  for (int off = 32; off > 0; off >>= 1) {
    const float mo = __shfl_down(m, off);
    const float so = __shfl_down(ss, off);
    const float mn = fmaxf(m, mo);
    ss = ss * __expf(m - mn) + so * __expf(mo - mn);
    m = mn;
  }
  if ((threadIdx.x & 63) == 0) { wm[threadIdx.x >> 6] = m; wss[threadIdx.x >> 6] = ss; }
  __syncthreads();
  if (threadIdx.x == 0) {
    float M = wm[0], S = wss[0];
#pragma unroll
    for (int q = 1; q < 4; ++q) {
      const float mn = fmaxf(M, wm[q]);
      S = S * __expf(M - mn) + wss[q] * __expf(wm[q] - mn);
      M = mn;
    }
    lossk[k] = (M + __logf(S)) - tgt_sh;
  }
}

__global__ void final_reduce(const float* __restrict__ lossk, float* __restrict__ out, int K)
{
  __shared__ float buf[256];
  float s = 0.f;
  for (int idx = threadIdx.x; idx < K; idx += 256) s += lossk[idx];
  buf[threadIdx.x] = s;
  __syncthreads();
  for (int off = 128; off > 0; off >>= 1) {
    if (threadIdx.x < off) buf[threadIdx.x] += buf[threadIdx.x + off];
    __syncthreads();
  }
  if (threadIdx.x == 0) out[0] = buf[0];
}

extern "C" void kernel_launch(void* const* d_in, const int* in_sizes, int n_in,
                              void* d_out, int out_size, void* d_ws, size_t ws_size,
                              hipStream_t stream)
{
  const float* emb  = (const float*)d_in[0];
  const float* wihF = (const float*)d_in[1];
  const float* whhF = (const float*)d_in[2];
  const float* bihF = (const float*)d_in[3];
  const float* bhhF = (const float*)d_in[4];
  const float* wihB = (const float*)d_in[5];
  const float* whhB = (const float*)d_in[6];
  const float* bihB = (const float*)d_in[7];
  const float* bhhB = (const float*)d_in[8];
  const float* dwih = (const float*)d_in[9];
  const float* dwhh = (const float*)d_in[10];
  const float* dbih = (const float*)d_in[11];
  const float* dbhh = (const float*)d_in[12];
  const int*   brks = (const int*)d_in[13];
  const int L = in_sizes[0] / 768;
  const int K = in_sizes[13];

  auto pad = [](size_t b) { return (b + 255) & ~(size_t)255; };
  const size_t szG   = pad((size_t)L * 1152 * 2);
  const size_t szOut = pad((size_t)L * 768 * 2);
  const size_t szGd  = pad((size_t)K * 2304 * 2);
  const size_t szDin = pad((size_t)K * 768 * 4);
  const size_t szDhs = pad((size_t)K * 768 * 4);
  const size_t szHin = pad(768 * 4);
  const size_t szHbf = pad(2 * 384 * 4);
  const size_t szCtr = pad((size_t)K * 4);
  const size_t szLk  = pad((size_t)K * 4);
  const size_t small = szOut + szGd + szDin + szDhs + szHin + szHbf + szCtr + szLk;
  const bool par = (ws_size >= 2 * szG + small);

  char* ws = (char*)d_ws;
  size_t off = 0;
  auto carve = [&](size_t bytes) -> char* { char* p = ws + off; off += bytes; return p; };
  unsigned short* Gf = (unsigned short*)carve(szG);
  unsigned short* Gb = par ? (unsigned short*)carve(szG) : Gf;
  unsigned short* outs = (unsigned short*)carve(szOut);
  unsigned short* Gd = (unsigned short*)carve(szGd);
  float* din = (float*)carve(szDin);
  float* dhs = (float*)carve(szDhs);
  float* hin = (float*)carve(szHin);
  unsigned int* hbuf = (unsigned int*)carve(szHbf);
  int* ctr = (int*)carve(szCtr);
  float* lk = (float*)carve(szLk);

  hipMemsetAsync(ctr, 0, (size_t)K * 4, stream);

  if (par) {
    gemm_nt_bias<<<dim3(L / 128, 9), 256, 0, stream>>>(emb, wihF, bihF, Gf, L, 1152, 768);
    gemm_nt_bias<<<dim3(L / 128, 9), 256, 0, stream>>>(emb, wihB, bihB, Gb, L, 1152, 768);
    enc_scan<<<2, 768, 0, stream>>>(whhF, bhhF, whhB, bhhB, Gf, Gb, outs, L, 0);
  } else {
    gemm_nt_bias<<<dim3(L / 128, 9), 256, 0, stream>>>(emb, wihF, bihF, Gf, L, 1152, 768);
    enc_scan<<<1, 768, 0, stream>>>(whhF, bhhF, whhB, bhhB, Gf, Gf, outs, L, 0);
    gemm_nt_bias<<<dim3(L / 128, 9), 256, 0, stream>>>(emb, wihB, bihB, Gf, L, 1152, 768);
    enc_scan<<<1, 768, 0, stream>>>(whhF, bhhF, whhB, bhhB, Gf, Gf, outs, L, 1);
  }
  gather_dec<<<K + 1, 256, 0, stream>>>(outs, brks, din, hin, L, K);
  gemm_nt_bias<<<dim3(K / 128, 18), 256, 0, stream>>>(din, dwih, dbih, Gd, K, 2304, 768);
  dec_scan<<<4, 768, 0, stream>>>(dwhh, dbhh, Gd, hin, hbuf, ctr, dhs, K);
  loss_kernel<<<K, 256, 0, stream>>>(outs, dhs, brks, lk, L);
  final_reduce<<<1, 256, 0, stream>>>(lk, (float*)d_out, K);
}

// Round 2
// 169474.084 us; speedup vs baseline: 1.7484x; 1.7484x over previous
//
#include <hip/hip_runtime.h>
#include <hip/hip_bf16.h>
#include <stdint.h>

typedef __attribute__((ext_vector_type(8))) short short8;
typedef __attribute__((ext_vector_type(4))) float f32x4;

__device__ __forceinline__ unsigned short f2bf(float f) {
  union { float f; unsigned u; } v; v.f = f;
  unsigned r = v.u + 0x7FFFu + ((v.u >> 16) & 1u);
  return (unsigned short)(r >> 16);
}
__device__ __forceinline__ float bf2f(unsigned short h) {
  union { unsigned u; float f; } v; v.u = ((unsigned)h) << 16;
  return v.f;
}
__device__ __forceinline__ float sigm(float x) {
  x = fminf(fmaxf(x, -30.f), 30.f);
  return 1.f / (1.f + __expf(-x));
}
__device__ __forceinline__ float tanh_(float x) {
  x = fminf(fmaxf(x, -15.f), 15.f);
  float t = __expf(2.f * x);
  return (t - 1.f) / (t + 1.f);
}
__device__ __forceinline__ short8 pack8(float4 u, float4 v) {
  short8 r;
  r[0] = (short)f2bf(u.x); r[1] = (short)f2bf(u.y); r[2] = (short)f2bf(u.z); r[3] = (short)f2bf(u.w);
  r[4] = (short)f2bf(v.x); r[5] = (short)f2bf(v.y); r[6] = (short)f2bf(v.z); r[7] = (short)f2bf(v.w);
  return r;
}

// C[M,N] bf16 = A[M,K] f32 * B[N,K]^T f32 + bias[N].  M,N mult of 128, K mult of 32.
__global__ __launch_bounds__(256) void gemm_nt_bias(
    const float* __restrict__ A, const float* __restrict__ B,
    const float* __restrict__ bias, unsigned short* __restrict__ C,
    int M, int N, int K)
{
  __shared__ __align__(16) short As[128 * 32];
  __shared__ __align__(16) short Bs[128 * 32];
  const int tid = threadIdx.x;
  const int lane = tid & 63, w = tid >> 6;
  const int brow = blockIdx.x * 128, bcol = blockIdx.y * 128;
  const int wrow = (w & 1) * 64, wcol = (w >> 1) * 64;
  const int c16 = lane & 15, kg = lane >> 4;
  f32x4 acc[4][4];
#pragma unroll
  for (int m = 0; m < 4; m++)
#pragma unroll
    for (int n = 0; n < 4; n++) { f32x4 z = {0.f, 0.f, 0.f, 0.f}; acc[m][n] = z; }

  const int lrow = tid >> 1, lk = (tid & 1) * 16;
  const float* ap = A + (size_t)(brow + lrow) * K + lk;
  const float* bp = B + (size_t)(bcol + lrow) * K + lk;
  short* asw = &As[lrow * 32 + lk];
  short* bsw = &Bs[lrow * 32 + lk];

  for (int kb = 0; kb < K; kb += 32) {
    float4 a0 = *(const float4*)(ap + kb);
    float4 a1 = *(const float4*)(ap + kb + 4);
    float4 a2 = *(const float4*)(ap + kb + 8);
    float4 a3 = *(const float4*)(ap + kb + 12);
    float4 b0 = *(const float4*)(bp + kb);
    float4 b1 = *(const float4*)(bp + kb + 4);
    float4 b2 = *(const float4*)(bp + kb + 8);
    float4 b3 = *(const float4*)(bp + kb + 12);
    __syncthreads();
    *(short8*)asw = pack8(a0, a1);
    *(short8*)(asw + 8) = pack8(a2, a3);
    *(short8*)bsw = pack8(b0, b1);
    *(short8*)(bsw + 8) = pack8(b2, b3);
    __syncthreads();
    short8 af[4], bf[4];
#pragma unroll
    for (int m = 0; m < 4; m++) af[m] = *(const short8*)&As[(wrow + m * 16 + c16) * 32 + kg * 8];
#pragma unroll
    for (int n = 0; n < 4; n++) bf[n] = *(const short8*)&Bs[(wcol + n * 16 + c16) * 32 + kg * 8];
#pragma unroll
    for (int m = 0; m < 4; m++)
#pragma unroll
      for (int n = 0; n < 4; n++)
        acc[m][n] = __builtin_amdgcn_mfma_f32_16x16x32_bf16(af[m], bf[n], acc[m][n], 0, 0, 0);
  }
#pragma unroll
  for (int n = 0; n < 4; n++) {
    const int col = bcol + wcol + n * 16 + c16;
    const float bv = bias[col];
#pragma unroll
    for (int m = 0; m < 4; m++) {
#pragma unroll
      for (int i = 0; i < 4; i++) {
        const int row = brow + wrow + m * 16 + kg * 4 + i;
        C[(size_t)row * N + col] = f2bf(acc[m][n][i] + bv);
      }
    }
  }
}

// Encoder GRU scan: per direction 3 WGs x 8 waves; each wave owns one 16-row
// gate-triple tile of Whh in VGPRs (144). h exchanged via outputs rows in L2,
// per-step counter flags. Blocks stride-8 so each direction maps to one XCD.
__global__ __launch_bounds__(512, 2) void enc_scan2(
    const float* __restrict__ WhhF, const float* __restrict__ bhhF,
    const float* __restrict__ WhhB, const float* __restrict__ bhhB,
    const unsigned short* __restrict__ Gf, const unsigned short* __restrict__ Gb,
    unsigned short* __restrict__ outputs, int* __restrict__ ctrE,
    const unsigned short* __restrict__ zerobuf, int L)
{
  const int bid = blockIdx.x;
  const int dir = bid & 7;
  if (dir >= 2) return;
  const int role = bid >> 3;  // 0..2
  const float* Whh = dir ? WhhB : WhhF;
  const float* bhh = dir ? bhhB : bhhF;
  const unsigned short* G = dir ? Gb : Gf;
  int* ctr = ctrE + (size_t)dir * L;

  const int tid = threadIdx.x, lane = tid & 63, w = tid >> 6;
  const int c16 = lane & 15, kg = lane >> 4;
  const int i = (role * 8 + w) * 16 + c16;  // 0..383
  const int ob = dir * 384;

  short8 wf[3][12];
  float bb[3];
#pragma unroll
  for (int g = 0; g < 3; g++) {
    const int j = g * 384 + i;
    bb[g] = bhh[j];
    const float* rowp = Whh + (size_t)j * 384 + kg * 8;
#pragma unroll
    for (int t = 0; t < 12; t++) {
      float4 x0 = *(const float4*)(rowp + t * 32);
      float4 x1 = *(const float4*)(rowp + t * 32 + 4);
      wf[g][t] = pack8(x0, x1);
    }
  }
  float h_own = 0.f;

  for (int si = 0; si < L; ++si) {
    const int s = dir ? (L - 1 - si) : si;
    const size_t gbase = (size_t)s * 1152 + i;
    const float gi0 = bf2f(G[gbase]);
    const float gi1 = bf2f(G[gbase + 384]);
    const float gi2 = bf2f(G[gbase + 768]);

    if (si > 0) {
      while (__hip_atomic_load(&ctr[si - 1], __ATOMIC_ACQUIRE, __HIP_MEMORY_SCOPE_AGENT) < 3)
        __builtin_amdgcn_s_sleep(1);
      __threadfence();
    }
    const int sp = dir ? (s + 1) : (s - 1);
    const unsigned short* hb =
        (si == 0) ? (zerobuf + kg * 8)
                  : (outputs + (size_t)sp * 768 + ob + kg * 8);

    f32x4 acc0 = {bb[0], bb[0], bb[0], bb[0]};
    f32x4 acc1 = {bb[1], bb[1], bb[1], bb[1]};
    f32x4 acc2 = {bb[2], bb[2], bb[2], bb[2]};
#pragma unroll
    for (int t = 0; t < 12; t++) {
      short8 a = *(const short8*)(hb + t * 32);
      acc0 = __builtin_amdgcn_mfma_f32_16x16x32_bf16(a, wf[0][t], acc0, 0, 0, 0);
      acc1 = __builtin_amdgcn_mfma_f32_16x16x32_bf16(a, wf[1][t], acc1, 0, 0, 0);
      acc2 = __builtin_amdgcn_mfma_f32_16x16x32_bf16(a, wf[2][t], acc2, 0, 0, 0);
    }
    const float r = sigm(gi0 + acc0[0]);
    const float z = sigm(gi1 + acc1[0]);
    const float n = tanh_(gi2 + r * acc2[0]);
    h_own = (1.f - z) * n + z * h_own;

    if (kg == 0) outputs[(size_t)s * 768 + ob + i] = f2bf(h_own);
    __threadfence();
    __syncthreads();
    if (tid == 0)
      __hip_atomic_fetch_add(&ctr[si], 1, __ATOMIC_RELEASE, __HIP_MEMORY_SCOPE_AGENT);
  }
}

// Decoder GRU scan: 12 WGs x 4 waves (1 wave/SIMD, 512-VGPR cap; wf=288).
// h exchanged via dechs rows; step 0 reads outputs[L-1].
__global__ __launch_bounds__(256, 1) void dec_scan2(
    const float* __restrict__ Whh, const float* __restrict__ bhh,
    const unsigned short* __restrict__ Gd, const unsigned short* __restrict__ outputs,
    unsigned short* __restrict__ dechs, int* __restrict__ ctrD, int L, int Ksteps)
{
  const int bid = blockIdx.x;
  if (bid & 7) return;
  const int role = bid >> 3;  // 0..11
  const int tid = threadIdx.x, lane = tid & 63, w = tid >> 6;  // w 0..3
  const int c16 = lane & 15, kg = lane >> 4;
  const int i = (role * 4 + w) * 16 + c16;  // 0..767

  short8 wf[3][24];
  float bb[3];
#pragma unroll
  for (int g = 0; g < 3; g++) {
    const int j = g * 768 + i;
    bb[g] = bhh[j];
    const float* rowp = Whh + (size_t)j * 768 + kg * 8;
#pragma unroll
    for (int t = 0; t < 24; t++) {
      float4 x0 = *(const float4*)(rowp + t * 32);
      float4 x1 = *(const float4*)(rowp + t * 32 + 4);
      wf[g][t] = pack8(x0, x1);
    }
  }
  const unsigned short* outLast = outputs + (size_t)(L - 1) * 768;
  float h_own = bf2f(outLast[i]);

  for (int s = 0; s < Ksteps; ++s) {
    const size_t gbase = (size_t)s * 2304 + i;
    const float gi0 = bf2f(Gd[gbase]);
    const float gi1 = bf2f(Gd[gbase + 768]);
    const float gi2 = bf2f(Gd[gbase + 1536]);

    if (s > 0) {
      while (__hip_atomic_load(&ctrD[s - 1], __ATOMIC_ACQUIRE, __HIP_MEMORY_SCOPE_AGENT) < 12)
        __builtin_amdgcn_s_sleep(1);
      __threadfence();
    }
    const unsigned short* hb =
        ((s == 0) ? outLast : (dechs + (size_t)(s - 1) * 768)) + kg * 8;

    f32x4 acc0 = {bb[0], bb[0], bb[0], bb[0]};
    f32x4 acc1 = {bb[1], bb[1], bb[1], bb[1]};
    f32x4 acc2 = {bb[2], bb[2], bb[2], bb[2]};
#pragma unroll
    for (int t = 0; t < 24; t++) {
      short8 a = *(const short8*)(hb + t * 32);
      acc0 = __builtin_amdgcn_mfma_f32_16x16x32_bf16(a, wf[0][t], acc0, 0, 0, 0);
      acc1 = __builtin_amdgcn_mfma_f32_16x16x32_bf16(a, wf[1][t], acc1, 0, 0, 0);
      acc2 = __builtin_amdgcn_mfma_f32_16x16x32_bf16(a, wf[2][t], acc2, 0, 0, 0);
    }
    const float r = sigm(gi0 + acc0[0]);
    const float z = sigm(gi1 + acc1[0]);
    const float n = tanh_(gi2 + r * acc2[0]);
    h_own = (1.f - z) * n + z * h_own;

    if (kg == 0) dechs[(size_t)s * 768 + i] = f2bf(h_own);
    __threadfence();
    __syncthreads();
    if (tid == 0)
      __hip_atomic_fetch_add(&ctrD[s], 1, __ATOMIC_RELEASE, __HIP_MEMORY_SCOPE_AGENT);
  }
}

__global__ void gather_dec(const unsigned short* __restrict__ outputs,
                           const int* __restrict__ breaks,
                           float* __restrict__ din, int L)
{
  const int b = blockIdx.x;
  const int start = b ? breaks[b - 1] : 0;
  const unsigned short* src = outputs + (size_t)start * 768;
  for (int d = threadIdx.x; d < 768; d += blockDim.x)
    din[(size_t)b * 768 + d] = bf2f(src[d]);
}

// C[M,N] f32 = A[M,K] bf16 * B[N,K]^T bf16 (scores = dechs . outputs^T)
__global__ __launch_bounds__(256) void gemm_score(
    const unsigned short* __restrict__ A, const unsigned short* __restrict__ B,
    float* __restrict__ C, int M, int N, int K)
{
  __shared__ __align__(16) short As[128 * 32];
  __shared__ __align__(16) short Bs[128 * 32];
  const int tid = threadIdx.x;
  const int lane = tid & 63, w = tid >> 6;
  const int brow = blockIdx.x * 128, bcol = blockIdx.y * 128;
  const int wrow = (w & 1) * 64, wcol = (w >> 1) * 64;
  const int c16 = lane & 15, kg = lane >> 4;
  f32x4 acc[4][4];
#pragma unroll
  for (int m = 0; m < 4; m++)
#pragma unroll
    for (int n = 0; n < 4; n++) { f32x4 z = {0.f, 0.f, 0.f, 0.f}; acc[m][n] = z; }

  const int lrow = tid >> 1, lk = (tid & 1) * 16;
  const unsigned short* ap = A + (size_t)(brow + lrow) * K + lk;
  const unsigned short* bp = B + (size_t)(bcol + lrow) * K + lk;
  short* asw = &As[lrow * 32 + lk];
  short* bsw = &Bs[lrow * 32 + lk];

  for (int kb = 0; kb < K; kb += 32) {
    short8 a0 = *(const short8*)(ap + kb);
    short8 a1 = *(const short8*)(ap + kb + 8);
    short8 b0 = *(const short8*)(bp + kb);
    short8 b1 = *(const short8*)(bp + kb + 8);
    __syncthreads();
    *(short8*)asw = a0;
    *(short8*)(asw + 8) = a1;
    *(short8*)bsw = b0;
    *(short8*)(bsw + 8) = b1;
    __syncthreads();
    short8 af[4], bf[4];
#pragma unroll
    for (int m = 0; m < 4; m++) af[m] = *(const short8*)&As[(wrow + m * 16 + c16) * 32 + kg * 8];
#pragma unroll
    for (int n = 0; n < 4; n++) bf[n] = *(const short8*)&Bs[(wcol + n * 16 + c16) * 32 + kg * 8];
#pragma unroll
    for (int m = 0; m < 4; m++)
#pragma unroll
      for (int n = 0; n < 4; n++)
        acc[m][n] = __builtin_amdgcn_mfma_f32_16x16x32_bf16(af[m], bf[n], acc[m][n], 0, 0, 0);
  }
#pragma unroll
  for (int n = 0; n < 4; n++) {
    const int col = bcol + wcol + n * 16 + c16;
#pragma unroll
    for (int m = 0; m < 4; m++) {
#pragma unroll
      for (int i = 0; i < 4; i++) {
        const int row = brow + wrow + m * 16 + kg * 4 + i;
        C[(size_t)row * N + col] = acc[m][n][i];
      }
    }
  }
}

// Masked logsumexp over scores[k][start..L) minus score at target.
__global__ __launch_bounds__(256) void loss2(
    const float* __restrict__ scores, const int* __restrict__ breaks,
    float* __restrict__ lossk, int L)
{
  const int k = blockIdx.x;
  const int start = k ? breaks[k - 1] : 0;
  const int target = breaks[k];
  const float* row = scores + (size_t)k * L;
  __shared__ float wm[4], wss[4];
  float m = -3.4e38f, ss = 0.f;
  for (int p = start + threadIdx.x; p < L; p += 256) {
    const float v = row[p];
    if (v > m) { ss = ss * __expf(m - v) + 1.f; m = v; }
    else ss += __expf(v - m);
  }
#pragma unroll
  for (int off = 32; off > 0; off >>= 1) {
    const float mo = __shfl_down(m, off);
    const float so = __shfl_down(ss, off);
    const float mn = fmaxf(m, mo);
    ss = ss * __expf(m - mn) + so * __expf(mo - mn);
    m = mn;
  }
  if ((threadIdx.x & 63) == 0) { wm[threadIdx.x >> 6] = m; wss[threadIdx.x >> 6] = ss; }
  __syncthreads();
  if (threadIdx.x == 0) {
    float M = wm[0], S = wss[0];
#pragma unroll
    for (int q = 1; q < 4; ++q) {
      const float mn = fmaxf(M, wm[q]);
      S = S * __expf(M - mn) + wss[q] * __expf(wm[q] - mn);
      M = mn;
    }
    lossk[k] = (M + __logf(S)) - row[target];
  }
}

__global__ void final_reduce(const float* __restrict__ lossk, float* __restrict__ out, int K)
{
  __shared__ float buf[256];
  float s = 0.f;
  for (int idx = threadIdx.x; idx < K; idx += 256) s += lossk[idx];
  buf[threadIdx.x] = s;
  __syncthreads();
  for (int off = 128; off > 0; off >>= 1) {
    if (threadIdx.x < off) buf[threadIdx.x] += buf[threadIdx.x + off];
    __syncthreads();
  }
  if (threadIdx.x == 0) out[0] = buf[0];
}

extern "C" void kernel_launch(void* const* d_in, const int* in_sizes, int n_in,
                              void* d_out, int out_size, void* d_ws, size_t ws_size,
                              hipStream_t stream)
{
  const float* emb  = (const float*)d_in[0];
  const float* wihF = (const float*)d_in[1];
  const float* whhF = (const float*)d_in[2];
  const float* bihF = (const float*)d_in[3];
  const float* bhhF = (const float*)d_in[4];
  const float* wihB = (const float*)d_in[5];
  const float* whhB = (const float*)d_in[6];
  const float* bihB = (const float*)d_in[7];
  const float* bhhB = (const float*)d_in[8];
  const float* dwih = (const float*)d_in[9];
  const float* dwhh = (const float*)d_in[10];
  const float* dbih = (const float*)d_in[11];
  const float* dbhh = (const float*)d_in[12];
  const int*   brks = (const int*)d_in[13];
  const int L = in_sizes[0] / 768;
  const int K = in_sizes[13];

  auto pad = [](size_t b) { return (b + 255) & ~(size_t)255; };
  const size_t szG   = pad((size_t)L * 1152 * 2);
  const size_t szOut = pad((size_t)L * 768 * 2);
  const size_t szGd  = pad((size_t)K * 2304 * 2);
  const size_t szDin = pad((size_t)K * 768 * 4);
  const size_t szDhs = pad((size_t)K * 768 * 2);
  const size_t szLk  = pad((size_t)K * 4);
  const size_t ctrBytes = (2 * (size_t)L + K) * 4 + 768 * 2;  // ctrE, ctrD, zerobuf
  const size_t szCtr = pad(ctrBytes);

  char* ws = (char*)d_ws;
  size_t off = 0;
  auto carve = [&](size_t bytes) -> char* { char* p = ws + off; off += bytes; return p; };
  unsigned short* Gf   = (unsigned short*)carve(szG);
  unsigned short* Gb   = (unsigned short*)carve(szG);
  unsigned short* outs = (unsigned short*)carve(szOut);
  unsigned short* Gd   = (unsigned short*)carve(szGd);
  float*          din  = (float*)carve(szDin);
  unsigned short* dhs  = (unsigned short*)carve(szDhs);
  float*          lk   = (float*)carve(szLk);
  int*            ctrE = (int*)carve(szCtr);
  int*            ctrD = ctrE + 2 * (size_t)L;
  unsigned short* zbuf = (unsigned short*)((char*)ctrE + (2 * (size_t)L + K) * 4);
  float* scores = (float*)Gf;  // alias: Gf dead after enc_scan2; 512*L*4 <= szG

  hipMemsetAsync(ctrE, 0, ctrBytes, stream);

  gemm_nt_bias<<<dim3(L / 128, 9), 256, 0, stream>>>(emb, wihF, bihF, Gf, L, 1152, 768);
  gemm_nt_bias<<<dim3(L / 128, 9), 256, 0, stream>>>(emb, wihB, bihB, Gb, L, 1152, 768);
  enc_scan2<<<24, 512, 0, stream>>>(whhF, bhhF, whhB, bhhB, Gf, Gb, outs, ctrE, zbuf, L);
  gather_dec<<<K, 256, 0, stream>>>(outs, brks, din, L);
  gemm_nt_bias<<<dim3(K / 128, 18), 256, 0, stream>>>(din, dwih, dbih, Gd, K, 2304, 768);
  dec_scan2<<<96, 256, 0, stream>>>(dwhh, dbhh, Gd, outs, dhs, ctrD, L, K);
  gemm_score<<<dim3(K / 128, L / 128), 256, 0, stream>>>(dhs, outs, scores, K, L, 768);
  loss2<<<K, 256, 0, stream>>>(scores, brks, lk, L);
  final_reduce<<<1, 256, 0, stream>>>(lk, (float*)d_out, K);
}